// Round 17
// baseline (181.688 us; speedup 1.0000x reference)
//
#include <hip/hip_runtime.h>
#include <stdint.h>

// Fused MHA: out = softmax_causal((xq Wq^T)(xk Wk^T)^T / 8) (xv Wv^T) Wo^T
// B=4 S=2048 E=1024 H=16 D=64.
// Workspace layout:
//   [0,16)  AO (attn output, bf16)
//   [48,50) Wqb [50,52) Wkb [52,54) Wvb [54,56) Wob
//   [56,72) Qp  [72,88) Kp  [88,104) Vt (per-head transposed V [b,h,d,s],
//           s-columns INTERLEAVED within each 32-block)
// Round-17: the round-16 merged-QK dispatch accidentally kept the T4
// double-buffer (64KB LDS -> 2 blocks/CU cap; LDS_Block_Size=65536 in the
// profile) so the TLP experiment never ran. Fix: merged QK now uses the
// 1-phase 32KB core (round-13 measured-good body) -> 1024 blocks all
// co-resident at 4-5 blocks/CU. V and WO stay on the T4 core (at 512-block
// grids LDS doesn't cost residency and T4 measured +1us/GEMM).
// Attn: round-13 kernel unchanged (84% combined issue = near ceiling).

#define LOG2E 1.44269504088896340736f

typedef __bf16 bf16;
typedef __attribute__((ext_vector_type(8))) __bf16 bf16x8;
typedef __attribute__((ext_vector_type(4))) __bf16 bf16x4;
typedef __attribute__((ext_vector_type(4))) float f32x4;

static constexpr int Sq = 2048, Eq = 1024;

__device__ __forceinline__ f32x4 mfma16(bf16x8 a, bf16x8 b, f32x4 c) {
  return __builtin_amdgcn_mfma_f32_16x16x32_bf16(a, b, c, 0, 0, 0);
}

// bare v_exp_f32 (2^x); args bounded, masked -1e30 underflows to 0.
__device__ __forceinline__ float fexp2(float x) {
  return __builtin_amdgcn_exp2f(x);
}

__device__ __forceinline__ void gload16(const bf16* g, bf16* l) {
  __builtin_amdgcn_global_load_lds(
      (const __attribute__((address_space(1))) void*)g,
      (__attribute__((address_space(3))) void*)l, 16, 0, 0);
}

__device__ __forceinline__ bf16x8 scale8(bf16x8 v, float s) {
  bf16x8 o;
#pragma unroll
  for (int i = 0; i < 8; ++i) o[i] = (bf16)((float)v[i] * s);
  return o;
}

__device__ __forceinline__ void store4(bf16* p, f32x4 a, float s) {
  bf16x4 v;
#pragma unroll
  for (int rg = 0; rg < 4; ++rg) v[rg] = (bf16)(a[rg] * s);
  *(bf16x4*)p = v;
}

__device__ __forceinline__ bf16x8 cvt8(const float4& a, const float4& b) {
  bf16x8 v;
  v[0] = (bf16)a.x; v[1] = (bf16)a.y; v[2] = (bf16)a.z; v[3] = (bf16)a.w;
  v[4] = (bf16)b.x; v[5] = (bf16)b.y; v[6] = (bf16)b.z; v[7] = (bf16)b.w;
  return v;
}

// ---------------- weight cast fp32 -> bf16 (4 tensors, 2^17 x8 each) ------
__global__ void cast_w4(const float* __restrict__ a, const float* __restrict__ b,
                        const float* __restrict__ c, const float* __restrict__ d,
                        bf16* __restrict__ oa, bf16* __restrict__ ob,
                        bf16* __restrict__ oc, bf16* __restrict__ od) {
  int i = blockIdx.x * blockDim.x + threadIdx.x;
  int sel = i >> 17, off = i & ((1 << 17) - 1);
  const float* src = sel == 0 ? a : sel == 1 ? b : sel == 2 ? c : d;
  bf16* dst = sel == 0 ? oa : sel == 1 ? ob : sel == 2 ? oc : od;
  const float4* p = (const float4*)src;
  ((bf16x8*)dst)[off] = cvt8(p[off * 2], p[off * 2 + 1]);
}

// ---------------- 1-phase GEMM core (32KB LDS): high-residency variant -----
// C_bf16[M,N] = A_f32[M,K] * W_bf16[N,K]^T. 128x128 tile, BK=64, 4 waves x
// 64x64. A fp32 cast fused (float4->cvt->ds_write); B via gload_lds w=16.
// Round-13 measured-good body, wg passed in by the dispatch wrapper.
__device__ __forceinline__ void gemm1_core(const float* __restrict__ Af,
                                           const bf16* __restrict__ W,
                                           bf16* __restrict__ C, int wg,
                                           bf16* Alds, bf16* Blds) {
  int tm = wg >> 3, tn = wg & 7;  // 64 x 8 tiles
  int tid = threadIdx.x;
  int l = tid & 63, wv = tid >> 6;
  int wm = wv >> 1, wn = wv & 1;
  int l15 = l & 15, lg = l >> 4;

  f32x4 acc[4][4] = {};
  const size_t arow = (size_t)tm * 128, brow = (size_t)tn * 128;

  for (int k0 = 0; k0 < 1024; k0 += 64) {
#pragma unroll
    for (int j = 0; j < 4; ++j) {
      int loc = tid * 16 + j * 4096;
      int r = loc >> 7;
      int c = (loc & 127) >> 1;
      gload16(W + (brow + r) * 1024 + k0 + c, (bf16*)((char*)Blds + loc));
    }
#pragma unroll
    for (int j = 0; j < 4; ++j) {
      int row = (tid >> 3) + j * 32;
      int colf = (tid & 7) * 8;
      const float4* ap = (const float4*)(Af + (arow + row) * 1024 + k0 + colf);
      float4 a0 = ap[0], a1 = ap[1];
      *(bf16x8*)(Alds + row * 64 + colf) = cvt8(a0, a1);
    }
    __syncthreads();
#pragma unroll
    for (int kk = 0; kk < 2; ++kk) {
      bf16x8 af[4], bfr[4];
#pragma unroll
      for (int t = 0; t < 4; ++t) {
        int ma = wm * 64 + t * 16 + l15;
        af[t] = *(const bf16x8*)((const char*)Alds + ma * 128 + 16 * lg + 64 * kk);
        int nb = wn * 64 + t * 16 + l15;
        bfr[t] = *(const bf16x8*)((const char*)Blds + nb * 128 + 16 * lg + 64 * kk);
      }
#pragma unroll
      for (int mt = 0; mt < 4; ++mt)
#pragma unroll
        for (int nt = 0; nt < 4; ++nt)
          acc[mt][nt] = mfma16(af[mt], bfr[nt], acc[mt][nt]);
    }
    __syncthreads();
  }

  int mbase = tm * 128 + wm * 64;
  int nbase = tn * 128 + wn * 64;
#pragma unroll
  for (int mt = 0; mt < 4; ++mt)
#pragma unroll
    for (int nt = 0; nt < 4; ++nt) {
      int m0 = mbase + mt * 16 + (lg << 2);
      int n = nbase + nt * 16 + l15;
#pragma unroll
      for (int rg = 0; rg < 4; ++rg)
        C[(size_t)(m0 + rg) * 1024 + n] = (bf16)acc[mt][nt][rg];
    }
}

// Merged Q+K projections: 1024 blocks, 32KB LDS -> 4-5 blocks/CU, ALL
// co-resident (the pure-TLP lever). Parity XCD partition: Q on even XCDs,
// K on odd; per half, wg = (sub&3)*128 + (sub>>2) keeps same-A-panel
// blocks adjacent on one XCD (instantaneous per-XCD set ~1MB << 4MB L2).
__global__ __launch_bounds__(256) void gemm_qk(
    const float* __restrict__ Aq, const float* __restrict__ Ak,
    const bf16* __restrict__ Wq, const bf16* __restrict__ Wk,
    bf16* __restrict__ Qp, bf16* __restrict__ Kp) {
  __shared__ __align__(16) bf16 Alds[128 * 64];
  __shared__ __align__(16) bf16 Blds[128 * 64];
  int bid = blockIdx.x;
  int which = bid & 1;
  int sub = bid >> 1;                     // 0..511
  int wg = (sub & 3) * 128 + (sub >> 2);  // bijective, panel-adjacent
  gemm1_core(which ? Ak : Aq, which ? Wk : Wq, which ? Kp : Qp, wg, Alds,
             Blds);
}

// ---------------- T4 GEMM core (64KB LDS, counted-vmcnt) -- V and WO ------
// Round-14 measured-best at 512-block grids (residency there is grid-capped
// at 2/CU regardless of LDS, and T4 measured +1us/GEMM).
// AFP32=1: A fp32 (8 float4 loads). AFP32=0: A bf16 (4 bf16x8 loads).
// MODE 1: Vt transposed+interleaved. MODE 2: C f32.
template <int MODE, int AFP32>
__global__ __launch_bounds__(256) void gemm_p2(const void* __restrict__ Ain,
                                               const bf16* __restrict__ W,
                                               void* __restrict__ Cout) {
  __shared__ __align__(16) bf16 Alds[2][128 * 64];
  __shared__ __align__(16) bf16 Blds[2][128 * 64];

  int bid = blockIdx.x;
  int wg = (bid & 7) * 64 + (bid >> 3);  // XCD swizzle (512%8==0)
  int tm = wg >> 3, tn = wg & 7;
  int tid = threadIdx.x;
  int l = tid & 63, wv = tid >> 6;
  int wm = wv >> 1, wn = wv & 1;
  int l15 = l & 15, lg = l >> 4;

  f32x4 acc[4][4] = {};
  const size_t arow = (size_t)tm * 128, brow = (size_t)tn * 128;
  const float* Af = (const float*)Ain;
  const bf16* Ab = (const bf16*)Ain;
  const int arow_t = tid >> 3;
  const int acol_t = (tid & 7) * 8;

  float4 a0[4], a1[4];
  bf16x8 ab[4];

#define ISSUEA(k0_)                                                          \
  do {                                                                       \
    if (AFP32) {                                                             \
      _Pragma("unroll") for (int j = 0; j < 4; ++j) {                        \
        const float4* ap = (const float4*)(Af + (arow + arow_t + j * 32) *   \
                                                    1024 + (k0_) + acol_t);  \
        a0[j] = ap[0]; a1[j] = ap[1];                                        \
      }                                                                      \
    } else {                                                                 \
      _Pragma("unroll") for (int j = 0; j < 4; ++j) {                        \
        ab[j] = *(const bf16x8*)(Ab + (arow + arow_t + j * 32) * 1024 +      \
                                 (k0_) + acol_t);                            \
      }                                                                      \
    }                                                                        \
  } while (0)

#define WRITEA(bufp)                                                         \
  do {                                                                       \
    _Pragma("unroll") for (int j = 0; j < 4; ++j) {                          \
      *(bf16x8*)(Alds[bufp] + (arow_t + j * 32) * 64 + acol_t) =             \
          AFP32 ? cvt8(a0[j], a1[j]) : ab[j];                                \
    }                                                                        \
  } while (0)

#define ISSUEB(k0_, bufp)                                                    \
  do {                                                                       \
    _Pragma("unroll") for (int j = 0; j < 4; ++j) {                          \
      int loc = tid * 16 + j * 4096;                                         \
      int r = loc >> 7;                                                      \
      int c = (loc & 127) >> 1;                                              \
      gload16(W + (brow + r) * 1024 + (k0_) + c,                             \
              (bf16*)((char*)Blds[bufp] + loc));                             \
    }                                                                        \
  } while (0)

#define COMPUTE(cb)                                                          \
  do {                                                                       \
    _Pragma("unroll") for (int kk = 0; kk < 2; ++kk) {                       \
      bf16x8 af[4], bfr[4];                                                  \
      _Pragma("unroll") for (int t = 0; t < 4; ++t) {                        \
        int ma = wm * 64 + t * 16 + l15;                                     \
        af[t] = *(const bf16x8*)((const char*)Alds[cb] + ma * 128 +          \
                                 16 * lg + 64 * kk);                         \
        int nb = wn * 64 + t * 16 + l15;                                     \
        bfr[t] = *(const bf16x8*)((const char*)Blds[cb] + nb * 128 +         \
                                  16 * lg + 64 * kk);                        \
      }                                                                      \
      _Pragma("unroll") for (int mt = 0; mt < 4; ++mt)                       \
          _Pragma("unroll") for (int nt = 0; nt < 4; ++nt)                   \
              acc[mt][nt] = mfma16(af[mt], bfr[nt], acc[mt][nt]);            \
    }                                                                        \
  } while (0)

  ISSUEA(0);
  ISSUEB(0, 0);
  asm volatile("s_waitcnt vmcnt(4)" ::: "memory");
  WRITEA(0);

  int cur = 0;
  for (int step = 0; step < 16; ++step) {
    if (step < 15) {
      ISSUEA((step + 1) * 64);
      if (AFP32)
        asm volatile("s_waitcnt vmcnt(8) lgkmcnt(0)\n\ts_barrier" ::: "memory");
      else
        asm volatile("s_waitcnt vmcnt(4) lgkmcnt(0)\n\ts_barrier" ::: "memory");
      ISSUEB((step + 1) * 64, cur ^ 1);
    } else {
      asm volatile("s_waitcnt vmcnt(0) lgkmcnt(0)\n\ts_barrier" ::: "memory");
    }
    COMPUTE(cur);
    if (step < 15) {
      asm volatile("s_waitcnt vmcnt(4)" ::: "memory");
      WRITEA(cur ^ 1);
      cur ^= 1;
    }
  }
#undef ISSUEA
#undef WRITEA
#undef ISSUEB
#undef COMPUTE

  int mbase = tm * 128 + wm * 64;
  int nbase = tn * 128 + wn * 64;
  if (MODE == 2) {
#pragma unroll
    for (int mt = 0; mt < 4; ++mt)
#pragma unroll
      for (int nt = 0; nt < 4; ++nt) {
        int m0 = mbase + mt * 16 + (lg << 2);
        int n = nbase + nt * 16 + l15;
#pragma unroll
        for (int rg = 0; rg < 4; ++rg)
          ((float*)Cout)[(size_t)(m0 + rg) * 1024 + n] = acc[mt][nt][rg];
      }
  } else {  // MODE 1: Vt[(b*16+h)*64 + d][pos(s)], interleaved columns
#pragma unroll
    for (int mt = 0; mt < 4; ++mt)
#pragma unroll
      for (int nt = 0; nt < 4; ++nt) {
        int m0 = mbase + mt * 16 + (lg << 2);
        int n = nbase + nt * 16 + l15;
        bf16x4 vv;
#pragma unroll
        for (int rg = 0; rg < 4; ++rg) vv[rg] = (bf16)acc[mt][nt][rg];
        int bb = m0 >> 11, s0 = m0 & 2047;  // s0 % 4 == 0
        int sp = (s0 & ~31) | (((s0 >> 4) & 1) << 2) | (((s0 >> 2) & 3) << 3);
        size_t off =
            ((size_t)((bb * 16 + (n >> 6)) * 64 + (n & 63))) * 2048 + sp;
        *(bf16x4*)((bf16*)Cout + off) = vv;
      }
  }
}

// ---------------- causal flash attention (1024 uniform blocks) -------------
// Block = (b,h, 64-row q-tile pair {t, 31-t}): seg A = tile t (t+1 chunks),
// seg B = tile 31-t (32-t chunks) -> EXACTLY 33 staged chunks per block,
// 4 waves x 16 q-rows. Depth-1 LDS double-buffer + __syncthreads.
// global_load_lds w=16 with XOR-swizzle pre-applied on the global source;
// swapped QK^T + static-max softmax (C=6 in MFMA C-init); bare v_exp_f32;
// row-sum via mfma(ones,P); V single-b128 reads via interleaved Vt.
// T5: setprio(1) around MFMA clusters. UNCHANGED from round 13.
__global__ __launch_bounds__(256) void attn_kernel(
    const bf16* __restrict__ Qp, const bf16* __restrict__ Kp,
    const bf16* __restrict__ Vt, bf16* __restrict__ AO) {
  __shared__ __align__(16) bf16 sm[2][2][4096];  // [buf][K|V][64 x 128B]

  int bid = blockIdx.x;                           // 1024
  int bh = ((bid & 7) << 3) | ((bid >> 3) & 7);   // 8 heads per XCD
  int t = bid >> 6;                               // 0..15
  int b = bh >> 4, h = bh & 15;
  int tid = threadIdx.x;
  int w = tid >> 6, l = tid & 63;
  int l15 = l & 15, lg = l >> 4;

  const int ncA = t + 1;                          // seg-A chunks
  const int NC = 33;                              // total staged chunks
  const float sc = 0.125f * LOG2E;
  bf16 one1 = (bf16)1.0f;
  bf16x8 ones = {one1, one1, one1, one1, one1, one1, one1, one1};

  const bf16* Kbase = Kp + (size_t)(b * 2048) * 1024 + h * 64;
  const bf16* Vbase = Vt + (size_t)(bh * 64) * 2048;

  // segment-mutable state (seg A: tile t)
  int qw0 = 64 * t + w * 16;
  int qg0 = qw0 + l15;
  const bf16* qp_ = Qp + (size_t)(b * 2048 + qw0 + l15) * 1024 + h * 64 + 8 * lg;
  bf16x8 q00 = scale8(*(const bf16x8*)qp_, sc);
  bf16x8 q01 = scale8(*(const bf16x8*)(qp_ + 32), sc);
  f32x4 r0 = {0.f, 0.f, 0.f, 0.f};
  f32x4 o0[4] = {};

#define STAGE(c_, bufp)                                                     \
  do {                                                                      \
    int _c = (c_);                                                          \
    _Pragma("unroll") for (int jj = 0; jj < 2; ++jj) {                      \
      int loc = tid * 16 + jj * 4096;                                       \
      int row = loc >> 7, u = (loc >> 4) & 7;                               \
      int sel = (u ^ (row & 7)) << 3;                                       \
      gload16(Kbase + (size_t)(_c * 64 + row) * 1024 + sel,                 \
              (bf16*)((char*)sm[bufp][0] + loc));                           \
      gload16(Vbase + (size_t)row * 2048 + _c * 64 + sel,                   \
              (bf16*)((char*)sm[bufp][1] + loc));                           \
    }                                                                       \
  } while (0)

#define CHUNKC(c_, last_)                                                   \
  do {                                                                      \
    const int _c = (c_);                                                    \
    const char* lK = (const char*)sm[cur][0];                               \
    const char* lV = (const char*)sm[cur][1];                               \
    const f32x4 cinit = {-6.f, -6.f, -6.f, -6.f};                           \
    f32x4 s[4];                                                             \
    __builtin_amdgcn_s_setprio(1);                                          \
    _Pragma("unroll") for (int kt = 0; kt < 4; ++kt) {                      \
      int row = kt * 16 + l15, sw = (row & 7) << 4;                         \
      const char* kb = lK + row * 128;                                      \
      bf16x8 kf0 = *(const bf16x8*)(kb + ((lg * 16) ^ sw));                 \
      bf16x8 kf1 = *(const bf16x8*)(kb + ((64 + lg * 16) ^ sw));            \
      s[kt] = mfma16(kf1, q01, mfma16(kf0, q00, cinit));                    \
    }                                                                       \
    __builtin_amdgcn_s_setprio(0);                                          \
    if (last_) {                                                            \
      _Pragma("unroll") for (int kt = 0; kt < 4; ++kt)                      \
          _Pragma("unroll") for (int rg = 0; rg < 4; ++rg) {                \
        int kg = _c * 64 + kt * 16 + 4 * lg + rg;                           \
        if (kg > qg0) s[kt][rg] = -1e30f;                                   \
      }                                                                     \
    }                                                                       \
    bf16x8 plo, phi;                                                        \
    _Pragma("unroll") for (int rg = 0; rg < 4; ++rg) {                      \
      plo[rg] = (bf16)fexp2(s[0][rg]);                                      \
      plo[rg + 4] = (bf16)fexp2(s[1][rg]);                                  \
      phi[rg] = (bf16)fexp2(s[2][rg]);                                      \
      phi[rg + 4] = (bf16)fexp2(s[3][rg]);                                  \
    }                                                                       \
    __builtin_amdgcn_s_setprio(1);                                          \
    r0 = mfma16(ones, phi, mfma16(ones, plo, r0));                          \
    _Pragma("unroll") for (int dt = 0; dt < 4; ++dt) {                      \
      int row = dt * 16 + l15, sw = (row & 7) << 4;                         \
      const char* vb = lV + row * 128;                                      \
      bf16x8 vf0 = *(const bf16x8*)(vb + ((lg * 16) ^ sw));                 \
      bf16x8 vf1 = *(const bf16x8*)(vb + ((64 + lg * 16) ^ sw));            \
      o0[dt] = mfma16(vf1, phi, mfma16(vf0, plo, o0[dt]));                  \
    }                                                                       \
    __builtin_amdgcn_s_setprio(0);                                          \
  } while (0)

#define STOREOUT()                                                          \
  do {                                                                      \
    float inv = 1.0f / r0[0];                                               \
    bf16* ob = AO + (size_t)(b * 2048 + qw0 + l15) * 1024 + h * 64 + 4 * lg; \
    _Pragma("unroll") for (int dt = 0; dt < 4; ++dt)                        \
        store4(ob + dt * 16, o0[dt], inv);                                  \
  } while (0)

  STAGE(0, 0);
  __syncthreads();
  int cur = 0;

  for (int g = 0; g < NC; ++g) {
    if (g + 1 < NC) {
      int gn = g + 1;
      STAGE(gn < ncA ? gn : gn - ncA, cur ^ 1);
    }
    if (g == ncA) {  // segment switch: store tile t, start tile 31-t
      STOREOUT();
      qw0 = 64 * (31 - t) + w * 16;
      qg0 = qw0 + l15;
      qp_ = Qp + (size_t)(b * 2048 + qw0 + l15) * 1024 + h * 64 + 8 * lg;
      q00 = scale8(*(const bf16x8*)qp_, sc);
      q01 = scale8(*(const bf16x8*)(qp_ + 32), sc);
      r0 = f32x4{0.f, 0.f, 0.f, 0.f};
#pragma unroll
      for (int dt = 0; dt < 4; ++dt) o0[dt] = r0;
    }
    int c = g < ncA ? g : g - ncA;
    bool last = (g == ncA - 1) || (g == NC - 1);
    CHUNKC(c, last);
    __syncthreads();
    cur ^= 1;
  }
  STOREOUT();
#undef STAGE
#undef CHUNKC
#undef STOREOUT
}

extern "C" void kernel_launch(void* const* d_in, const int* in_sizes, int n_in,
                              void* d_out, int out_size, void* d_ws, size_t ws_size,
                              hipStream_t stream) {
  (void)in_sizes; (void)n_in; (void)out_size; (void)ws_size;
  const float* dq = (const float*)d_in[0];
  const float* dk = (const float*)d_in[1];
  const float* dv = (const float*)d_in[2];
  const float* wq = (const float*)d_in[3];
  const float* wk = (const float*)d_in[4];
  const float* wv = (const float*)d_in[5];
  const float* wo = (const float*)d_in[6];

  char* ws = (char*)d_ws;
  const size_t MB = 1u << 20;
  bf16* AO  = (bf16*)(ws + 0 * MB);
  bf16* wqb = (bf16*)(ws + 48 * MB);
  bf16* wkb = (bf16*)(ws + 50 * MB);
  bf16* wvb = (bf16*)(ws + 52 * MB);
  bf16* wob = (bf16*)(ws + 54 * MB);
  bf16* Qp  = (bf16*)(ws + 56 * MB);
  bf16* Kp  = (bf16*)(ws + 72 * MB);
  bf16* Vt  = (bf16*)(ws + 88 * MB);

  cast_w4<<<4 * 512, 256, 0, stream>>>(wq, wk, wv, wo, wqb, wkb, wvb, wob);
  gemm_qk<<<1024, 256, 0, stream>>>(dq, dk, wqb, wkb, Qp, Kp);
  gemm_p2<1, 1><<<512, 256, 0, stream>>>(dv, wvb, (void*)Vt);
  attn_kernel<<<1024, 256, 0, stream>>>(Qp, Kp, Vt, AO);
  gemm_p2<2, 0><<<512, 256, 0, stream>>>(AO, wob, d_out);
}

// Round 18
// 173.028 us; speedup vs baseline: 1.0501x; 1.0501x over previous
//
#include <hip/hip_runtime.h>
#include <stdint.h>

// Fused MHA: out = softmax_causal((xq Wq^T)(xk Wk^T)^T / 8) (xv Wv^T) Wo^T
// B=4 S=2048 E=1024 H=16 D=64.
// Workspace layout:
//   [0,16)  AO (attn output, bf16)
//   [48,50) Wqb [50,52) Wkb [52,54) Wvb [54,56) Wob
//   [56,72) Qp  [72,88) Kp  [88,104) Vt (per-head transposed V [b,h,d,s],
//           s-columns INTERLEAVED within each 32-block)
// Round-18 = round-16 best config (178.6us) + T2 XOR-swizzle in the GEMM
// core. Every GEMM all session carried 12.6M LDS bank-conflict cycles
// (16-way on 128B-stride ds_read_b128; ~20us/GEMM serialized LDS) while
// the swizzled attn kernel shows 0. A: swizzled ds_write + swizzled read.
// B: pre-swizzled GLOBAL source (gload_lds writes linear; rule #21) +
// swizzled read. Attn: round-13 kernel unchanged.

#define LOG2E 1.44269504088896340736f

typedef __bf16 bf16;
typedef __attribute__((ext_vector_type(8))) __bf16 bf16x8;
typedef __attribute__((ext_vector_type(4))) __bf16 bf16x4;
typedef __attribute__((ext_vector_type(4))) float f32x4;

static constexpr int Sq = 2048, Eq = 1024;

__device__ __forceinline__ f32x4 mfma16(bf16x8 a, bf16x8 b, f32x4 c) {
  return __builtin_amdgcn_mfma_f32_16x16x32_bf16(a, b, c, 0, 0, 0);
}

// bare v_exp_f32 (2^x); args bounded, masked -1e30 underflows to 0.
__device__ __forceinline__ float fexp2(float x) {
  return __builtin_amdgcn_exp2f(x);
}

__device__ __forceinline__ void gload16(const bf16* g, bf16* l) {
  __builtin_amdgcn_global_load_lds(
      (const __attribute__((address_space(1))) void*)g,
      (__attribute__((address_space(3))) void*)l, 16, 0, 0);
}

__device__ __forceinline__ bf16x8 scale8(bf16x8 v, float s) {
  bf16x8 o;
#pragma unroll
  for (int i = 0; i < 8; ++i) o[i] = (bf16)((float)v[i] * s);
  return o;
}

__device__ __forceinline__ void store4(bf16* p, f32x4 a, float s) {
  bf16x4 v;
#pragma unroll
  for (int rg = 0; rg < 4; ++rg) v[rg] = (bf16)(a[rg] * s);
  *(bf16x4*)p = v;
}

__device__ __forceinline__ bf16x8 cvt8(const float4& a, const float4& b) {
  bf16x8 v;
  v[0] = (bf16)a.x; v[1] = (bf16)a.y; v[2] = (bf16)a.z; v[3] = (bf16)a.w;
  v[4] = (bf16)b.x; v[5] = (bf16)b.y; v[6] = (bf16)b.z; v[7] = (bf16)b.w;
  return v;
}

// ---------------- weight cast fp32 -> bf16 (4 tensors, 2^17 x8 each) ------
__global__ void cast_w4(const float* __restrict__ a, const float* __restrict__ b,
                        const float* __restrict__ c, const float* __restrict__ d,
                        bf16* __restrict__ oa, bf16* __restrict__ ob,
                        bf16* __restrict__ oc, bf16* __restrict__ od) {
  int i = blockIdx.x * blockDim.x + threadIdx.x;
  int sel = i >> 17, off = i & ((1 << 17) - 1);
  const float* src = sel == 0 ? a : sel == 1 ? b : sel == 2 ? c : d;
  bf16* dst = sel == 0 ? oa : sel == 1 ? ob : sel == 2 ? oc : od;
  const float4* p = (const float4*)src;
  ((bf16x8*)dst)[off] = cvt8(p[off * 2], p[off * 2 + 1]);
}

// ---------------- T4 GEMM core (64KB LDS, counted-vmcnt, T2-swizzled) -----
// C[M,N] = A[M,K] * W[N,K]^T. 128x128 tile, BK=64, 4 waves x 64x64.
// Per K-step: {issue A(k+1)->regs; vmcnt(NL)+lgkm(0)+s_barrier (A(k+1) in
// flight); issue B(k+1) gload_lds post-barrier; compute(k); vmcnt(4);
// cvt+ds_write A(k+1)}. T2: LDS byte offsets XOR (row&7)<<4 -- A swizzled
// at ds_write, B via pre-swizzled global source (linear gload_lds dest).
// AFP32=1: A fp32 (8 float4 loads). AFP32=0: A bf16 (4 bf16x8 loads).
// MODE 0: C bf16. MODE 1: Vt transposed+interleaved. MODE 2: C f32.
template <int MODE, int AFP32>
__device__ __forceinline__ void gemm_core(const void* __restrict__ Ain,
                                          const bf16* __restrict__ W,
                                          void* __restrict__ Cout, int wg,
                                          bf16 (*Alds)[128 * 64],
                                          bf16 (*Blds)[128 * 64]) {
  int tm = wg >> 3, tn = wg & 7;  // 64 x 8 tiles
  int tid = threadIdx.x;
  int l = tid & 63, wv = tid >> 6;
  int wm = wv >> 1, wn = wv & 1;
  int l15 = l & 15, lg = l >> 4;

  f32x4 acc[4][4] = {};
  const size_t arow = (size_t)tm * 128, brow = (size_t)tn * 128;
  const float* Af = (const float*)Ain;
  const bf16* Ab = (const bf16*)Ain;
  const int arow_t = tid >> 3;       // +j*32
  const int acol_t = (tid & 7) * 8;  // element col (8 elems = one 16B unit)

  float4 a0[4], a1[4];  // AFP32 staging
  bf16x8 ab[4];         // bf16 staging

#define ISSUEA(k0_)                                                          \
  do {                                                                       \
    if (AFP32) {                                                             \
      _Pragma("unroll") for (int j = 0; j < 4; ++j) {                        \
        const float4* ap = (const float4*)(Af + (arow + arow_t + j * 32) *   \
                                                    1024 + (k0_) + acol_t);  \
        a0[j] = ap[0]; a1[j] = ap[1];                                        \
      }                                                                      \
    } else {                                                                 \
      _Pragma("unroll") for (int j = 0; j < 4; ++j) {                        \
        ab[j] = *(const bf16x8*)(Ab + (arow + arow_t + j * 32) * 1024 +      \
                                 (k0_) + acol_t);                            \
      }                                                                      \
    }                                                                        \
  } while (0)

// swizzled A write: byte = row*128 + ((u)^(row&7))*16, u = tid&7
#define WRITEA(bufp)                                                         \
  do {                                                                       \
    _Pragma("unroll") for (int j = 0; j < 4; ++j) {                          \
      int row_ = arow_t + j * 32;                                            \
      int off_ = row_ * 128 + (((tid & 7) ^ (row_ & 7)) << 4);               \
      *(bf16x8*)((char*)Alds[bufp] + off_) =                                 \
          AFP32 ? cvt8(a0[j], a1[j]) : ab[j];                                \
    }                                                                        \
  } while (0)

// B: linear LDS dest, pre-swizzled global source unit (u ^ (r&7))
#define ISSUEB(k0_, bufp)                                                    \
  do {                                                                       \
    _Pragma("unroll") for (int j = 0; j < 4; ++j) {                          \
      int loc = tid * 16 + j * 4096;                                         \
      int r = loc >> 7;                                                      \
      int u = (loc >> 4) & 7;                                                \
      int c = (u ^ (r & 7)) << 3;                                            \
      gload16(W + (brow + r) * 1024 + (k0_) + c,                             \
              (bf16*)((char*)Blds[bufp] + loc));                             \
    }                                                                        \
  } while (0)

#define COMPUTE(cb)                                                          \
  do {                                                                       \
    _Pragma("unroll") for (int kk = 0; kk < 2; ++kk) {                       \
      bf16x8 af[4], bfr[4];                                                  \
      _Pragma("unroll") for (int t = 0; t < 4; ++t) {                        \
        int ma = wm * 64 + t * 16 + l15;                                     \
        int oa_ = (ma * 128 + 16 * lg + 64 * kk) ^ ((ma & 7) << 4);          \
        af[t] = *(const bf16x8*)((const char*)Alds[cb] + oa_);               \
        int nb = wn * 64 + t * 16 + l15;                                     \
        int ob_ = (nb * 128 + 16 * lg + 64 * kk) ^ ((nb & 7) << 4);          \
        bfr[t] = *(const bf16x8*)((const char*)Blds[cb] + ob_);              \
      }                                                                      \
      _Pragma("unroll") for (int mt = 0; mt < 4; ++mt)                       \
          _Pragma("unroll") for (int nt = 0; nt < 4; ++nt)                   \
              acc[mt][nt] = mfma16(af[mt], bfr[nt], acc[mt][nt]);            \
    }                                                                        \
  } while (0)

  // prologue: A(0)+B(0) issued; wait A only (B(0) still in flight)
  ISSUEA(0);
  ISSUEB(0, 0);
  asm volatile("s_waitcnt vmcnt(4)" ::: "memory");
  WRITEA(0);

  int cur = 0;
  for (int step = 0; step < 16; ++step) {
    if (step < 15) {
      ISSUEA((step + 1) * 64);  // in flight across the barrier
      if (AFP32)
        asm volatile("s_waitcnt vmcnt(8) lgkmcnt(0)\n\ts_barrier" ::: "memory");
      else
        asm volatile("s_waitcnt vmcnt(4) lgkmcnt(0)\n\ts_barrier" ::: "memory");
      ISSUEB((step + 1) * 64, cur ^ 1);  // hides under compute
    } else {
      asm volatile("s_waitcnt vmcnt(0) lgkmcnt(0)\n\ts_barrier" ::: "memory");
    }
    COMPUTE(cur);
    if (step < 15) {
      asm volatile("s_waitcnt vmcnt(4)" ::: "memory");  // A done, B in flight
      WRITEA(cur ^ 1);
      cur ^= 1;
    }
  }
#undef ISSUEA
#undef WRITEA
#undef ISSUEB
#undef COMPUTE

  int mbase = tm * 128 + wm * 64;
  int nbase = tn * 128 + wn * 64;
  if (MODE == 0 || MODE == 2) {
#pragma unroll
    for (int mt = 0; mt < 4; ++mt)
#pragma unroll
      for (int nt = 0; nt < 4; ++nt) {
        int m0 = mbase + mt * 16 + (lg << 2);
        int n = nbase + nt * 16 + l15;
#pragma unroll
        for (int rg = 0; rg < 4; ++rg) {
          if (MODE == 0)
            ((bf16*)Cout)[(size_t)(m0 + rg) * 1024 + n] = (bf16)acc[mt][nt][rg];
          else
            ((float*)Cout)[(size_t)(m0 + rg) * 1024 + n] = acc[mt][nt][rg];
        }
      }
  } else {  // MODE 1: Vt[(b*16+h)*64 + d][pos(s)], interleaved columns
#pragma unroll
    for (int mt = 0; mt < 4; ++mt)
#pragma unroll
      for (int nt = 0; nt < 4; ++nt) {
        int m0 = mbase + mt * 16 + (lg << 2);
        int n = nbase + nt * 16 + l15;
        bf16x4 vv;
#pragma unroll
        for (int rg = 0; rg < 4; ++rg) vv[rg] = (bf16)acc[mt][nt][rg];
        int bb = m0 >> 11, s0 = m0 & 2047;  // s0 % 4 == 0
        int sp = (s0 & ~31) | (((s0 >> 4) & 1) << 2) | (((s0 >> 2) & 3) << 3);
        size_t off =
            ((size_t)((bb * 16 + (n >> 6)) * 64 + (n & 63))) * 2048 + sp;
        *(bf16x4*)((bf16*)Cout + off) = vv;
      }
  }
}

// Standalone GEMM dispatch (512 blocks, XCD swizzle) -- V and WO.
template <int MODE, int AFP32>
__global__ __launch_bounds__(256) void gemm_p2(const void* __restrict__ Ain,
                                               const bf16* __restrict__ W,
                                               void* __restrict__ Cout) {
  __shared__ __align__(16) bf16 Alds[2][128 * 64];
  __shared__ __align__(16) bf16 Blds[2][128 * 64];
  int bid = blockIdx.x;
  int wg = (bid & 7) * 64 + (bid >> 3);  // XCD swizzle (512%8==0)
  gemm_core<MODE, AFP32>(Ain, W, Cout, wg, Alds, Blds);
}

// Merged Q+K projection dispatch (round-16 best): 1024 blocks, parity XCD
// partition (Q even XCDs, K odd), panel-adjacent wg.
__global__ __launch_bounds__(256) void gemm_qk(
    const float* __restrict__ Aq, const float* __restrict__ Ak,
    const bf16* __restrict__ Wq, const bf16* __restrict__ Wk,
    bf16* __restrict__ Qp, bf16* __restrict__ Kp) {
  __shared__ __align__(16) bf16 Alds[2][128 * 64];
  __shared__ __align__(16) bf16 Blds[2][128 * 64];
  int bid = blockIdx.x;
  int which = bid & 1;
  int sub = bid >> 1;                     // 0..511
  int wg = (sub & 3) * 128 + (sub >> 2);  // bijective, panel-adjacent
  gemm_core<0, 1>(which ? (const void*)Ak : (const void*)Aq,
                  which ? Wk : Wq, which ? (void*)Kp : (void*)Qp, wg, Alds,
                  Blds);
}

// ---------------- causal flash attention (1024 uniform blocks) -------------
// Block = (b,h, 64-row q-tile pair {t, 31-t}): seg A = tile t (t+1 chunks),
// seg B = tile 31-t (32-t chunks) -> EXACTLY 33 staged chunks per block,
// 4 waves x 16 q-rows. Depth-1 LDS double-buffer + __syncthreads.
// global_load_lds w=16 with XOR-swizzle pre-applied on the global source;
// swapped QK^T + static-max softmax (C=6 in MFMA C-init); bare v_exp_f32;
// row-sum via mfma(ones,P); V single-b128 reads via interleaved Vt.
// T5: setprio(1) around MFMA clusters. UNCHANGED from round 13.
__global__ __launch_bounds__(256) void attn_kernel(
    const bf16* __restrict__ Qp, const bf16* __restrict__ Kp,
    const bf16* __restrict__ Vt, bf16* __restrict__ AO) {
  __shared__ __align__(16) bf16 sm[2][2][4096];  // [buf][K|V][64 x 128B]

  int bid = blockIdx.x;                           // 1024
  int bh = ((bid & 7) << 3) | ((bid >> 3) & 7);   // 8 heads per XCD
  int t = bid >> 6;                               // 0..15
  int b = bh >> 4, h = bh & 15;
  int tid = threadIdx.x;
  int w = tid >> 6, l = tid & 63;
  int l15 = l & 15, lg = l >> 4;

  const int ncA = t + 1;                          // seg-A chunks
  const int NC = 33;                              // total staged chunks
  const float sc = 0.125f * LOG2E;
  bf16 one1 = (bf16)1.0f;
  bf16x8 ones = {one1, one1, one1, one1, one1, one1, one1, one1};

  const bf16* Kbase = Kp + (size_t)(b * 2048) * 1024 + h * 64;
  const bf16* Vbase = Vt + (size_t)(bh * 64) * 2048;

  // segment-mutable state (seg A: tile t)
  int qw0 = 64 * t + w * 16;
  int qg0 = qw0 + l15;
  const bf16* qp_ = Qp + (size_t)(b * 2048 + qw0 + l15) * 1024 + h * 64 + 8 * lg;
  bf16x8 q00 = scale8(*(const bf16x8*)qp_, sc);
  bf16x8 q01 = scale8(*(const bf16x8*)(qp_ + 32), sc);
  f32x4 r0 = {0.f, 0.f, 0.f, 0.f};
  f32x4 o0[4] = {};

#define STAGE(c_, bufp)                                                     \
  do {                                                                      \
    int _c = (c_);                                                          \
    _Pragma("unroll") for (int jj = 0; jj < 2; ++jj) {                      \
      int loc = tid * 16 + jj * 4096;                                       \
      int row = loc >> 7, u = (loc >> 4) & 7;                               \
      int sel = (u ^ (row & 7)) << 3;                                       \
      gload16(Kbase + (size_t)(_c * 64 + row) * 1024 + sel,                 \
              (bf16*)((char*)sm[bufp][0] + loc));                           \
      gload16(Vbase + (size_t)row * 2048 + _c * 64 + sel,                   \
              (bf16*)((char*)sm[bufp][1] + loc));                           \
    }                                                                       \
  } while (0)

#define CHUNKC(c_, last_)                                                   \
  do {                                                                      \
    const int _c = (c_);                                                    \
    const char* lK = (const char*)sm[cur][0];                               \
    const char* lV = (const char*)sm[cur][1];                               \
    const f32x4 cinit = {-6.f, -6.f, -6.f, -6.f};                           \
    f32x4 s[4];                                                             \
    __builtin_amdgcn_s_setprio(1);                                          \
    _Pragma("unroll") for (int kt = 0; kt < 4; ++kt) {                      \
      int row = kt * 16 + l15, sw = (row & 7) << 4;                         \
      const char* kb = lK + row * 128;                                      \
      bf16x8 kf0 = *(const bf16x8*)(kb + ((lg * 16) ^ sw));                 \
      bf16x8 kf1 = *(const bf16x8*)(kb + ((64 + lg * 16) ^ sw));            \
      s[kt] = mfma16(kf1, q01, mfma16(kf0, q00, cinit));                    \
    }                                                                       \
    __builtin_amdgcn_s_setprio(0);                                          \
    if (last_) {                                                            \
      _Pragma("unroll") for (int kt = 0; kt < 4; ++kt)                      \
          _Pragma("unroll") for (int rg = 0; rg < 4; ++rg) {                \
        int kg = _c * 64 + kt * 16 + 4 * lg + rg;                           \
        if (kg > qg0) s[kt][rg] = -1e30f;                                   \
      }                                                                     \
    }                                                                       \
    bf16x8 plo, phi;                                                        \
    _Pragma("unroll") for (int rg = 0; rg < 4; ++rg) {                      \
      plo[rg] = (bf16)fexp2(s[0][rg]);                                      \
      plo[rg + 4] = (bf16)fexp2(s[1][rg]);                                  \
      phi[rg] = (bf16)fexp2(s[2][rg]);                                      \
      phi[rg + 4] = (bf16)fexp2(s[3][rg]);                                  \
    }                                                                       \
    __builtin_amdgcn_s_setprio(1);                                          \
    r0 = mfma16(ones, phi, mfma16(ones, plo, r0));                          \
    _Pragma("unroll") for (int dt = 0; dt < 4; ++dt) {                      \
      int row = dt * 16 + l15, sw = (row & 7) << 4;                         \
      const char* vb = lV + row * 128;                                      \
      bf16x8 vf0 = *(const bf16x8*)(vb + ((lg * 16) ^ sw));                 \
      bf16x8 vf1 = *(const bf16x8*)(vb + ((64 + lg * 16) ^ sw));            \
      o0[dt] = mfma16(vf1, phi, mfma16(vf0, plo, o0[dt]));                  \
    }                                                                       \
    __builtin_amdgcn_s_setprio(0);                                          \
  } while (0)

#define STOREOUT()                                                          \
  do {                                                                      \
    float inv = 1.0f / r0[0];                                               \
    bf16* ob = AO + (size_t)(b * 2048 + qw0 + l15) * 1024 + h * 64 + 4 * lg; \
    _Pragma("unroll") for (int dt = 0; dt < 4; ++dt)                        \
        store4(ob + dt * 16, o0[dt], inv);                                  \
  } while (0)

  STAGE(0, 0);
  __syncthreads();
  int cur = 0;

  for (int g = 0; g < NC; ++g) {
    if (g + 1 < NC) {
      int gn = g + 1;
      STAGE(gn < ncA ? gn : gn - ncA, cur ^ 1);
    }
    if (g == ncA) {  // segment switch: store tile t, start tile 31-t
      STOREOUT();
      qw0 = 64 * (31 - t) + w * 16;
      qg0 = qw0 + l15;
      qp_ = Qp + (size_t)(b * 2048 + qw0 + l15) * 1024 + h * 64 + 8 * lg;
      q00 = scale8(*(const bf16x8*)qp_, sc);
      q01 = scale8(*(const bf16x8*)(qp_ + 32), sc);
      r0 = f32x4{0.f, 0.f, 0.f, 0.f};
#pragma unroll
      for (int dt = 0; dt < 4; ++dt) o0[dt] = r0;
    }
    int c = g < ncA ? g : g - ncA;
    bool last = (g == ncA - 1) || (g == NC - 1);
    CHUNKC(c, last);
    __syncthreads();
    cur ^= 1;
  }
  STOREOUT();
#undef STAGE
#undef CHUNKC
#undef STOREOUT
}

extern "C" void kernel_launch(void* const* d_in, const int* in_sizes, int n_in,
                              void* d_out, int out_size, void* d_ws, size_t ws_size,
                              hipStream_t stream) {
  (void)in_sizes; (void)n_in; (void)out_size; (void)ws_size;
  const float* dq = (const float*)d_in[0];
  const float* dk = (const float*)d_in[1];
  const float* dv = (const float*)d_in[2];
  const float* wq = (const float*)d_in[3];
  const float* wk = (const float*)d_in[4];
  const float* wv = (const float*)d_in[5];
  const float* wo = (const float*)d_in[6];

  char* ws = (char*)d_ws;
  const size_t MB = 1u << 20;
  bf16* AO  = (bf16*)(ws + 0 * MB);
  bf16* wqb = (bf16*)(ws + 48 * MB);
  bf16* wkb = (bf16*)(ws + 50 * MB);
  bf16* wvb = (bf16*)(ws + 52 * MB);
  bf16* wob = (bf16*)(ws + 54 * MB);
  bf16* Qp  = (bf16*)(ws + 56 * MB);
  bf16* Kp  = (bf16*)(ws + 72 * MB);
  bf16* Vt  = (bf16*)(ws + 88 * MB);

  cast_w4<<<4 * 512, 256, 0, stream>>>(wq, wk, wv, wo, wqb, wkb, wvb, wob);
  gemm_qk<<<1024, 256, 0, stream>>>(dq, dk, wqb, wkb, Qp, Kp);
  gemm_p2<1, 1><<<512, 256, 0, stream>>>(dv, wvb, (void*)Vt);
  attn_kernel<<<1024, 256, 0, stream>>>(Qp, Kp, Vt, AO);
  gemm_p2<2, 0><<<512, 256, 0, stream>>>(AO, wob, d_out);
}